// Round 13
// baseline (449.622 us; speedup 1.0000x reference)
//
#include <hip/hip_runtime.h>
#include <hip/hip_bf16.h>

// Shapes (fixed by the problem)
#define VV 50000
#define EE 128
#define HH 128
#define OO 128
#define BB 64
#define TT 512

typedef __bf16 bf16_t;
typedef __attribute__((ext_vector_type(8))) __bf16 bf16x8;
typedef __attribute__((ext_vector_type(4))) __bf16 bf16x4;
typedef __attribute__((ext_vector_type(4))) float floatx4;

// exp2-prescale constants: sigmoid/tanh computed via v_exp_f32 (=2^x) with
// log2e folded into the r/z/n weight rows in k0 (r,z: -log2e; n: +2*log2e).
#define SC_RZ (-1.4426950408889634f)
#define SC_N  (2.8853900817779268f)

__device__ __forceinline__ bf16x8 ldb8(const bf16_t* p) {
    return *reinterpret_cast<const bf16x8*>(p);
}

// load 8 consecutive fp32, round to bf16 fragment (two float4 loads)
__device__ __forceinline__ bf16x8 ldf8_bf(const float* p) {
    const float4* q = reinterpret_cast<const float4*>(p);
    float4 u = q[0], v = q[1];
    bf16x8 r;
    r[0] = (__bf16)u.x; r[1] = (__bf16)u.y; r[2] = (__bf16)u.z; r[3] = (__bf16)u.w;
    r[4] = (__bf16)v.x; r[5] = (__bf16)v.y; r[6] = (__bf16)v.z; r[7] = (__bf16)v.w;
    return r;
}

__device__ __forceinline__ float fast_rcp(float x) { return __builtin_amdgcn_rcpf(x); }
__device__ __forceinline__ float exp2_f(float x) { return __builtin_amdgcn_exp2f(x); }
__device__ __forceinline__ float tanh_f(float x) {
    float e = __expf(2.0f * x);
    return 1.0f - 2.0f * fast_rcp(e + 1.0f);
}

// LDS-only barrier: wait LDS ops, sync — do NOT drain vmcnt (hist stores and
// gx ring-prefetch loads stay in flight across steps).
__device__ __forceinline__ void lds_barrier() {
    asm volatile("s_waitcnt lgkmcnt(0)\n\ts_barrier" ::: "memory");
}

// -------- K0: preconvert weights fp32->bf16 + fold gx bias (weights only).
__global__ __launch_bounds__(256) void k0_conv(
    const float* __restrict__ we,
    const float* __restrict__ wihf, const float* __restrict__ wihb,
    const float* __restrict__ whhf, const float* __restrict__ whhb,
    const float* __restrict__ wh2o,
    const float* __restrict__ bihf, const float* __restrict__ bhhf,
    const float* __restrict__ bihb, const float* __restrict__ bhhb,
    bf16_t* __restrict__ we_bf,
    bf16_t* __restrict__ wih_bf, bf16_t* __restrict__ whh_bf,
    bf16_t* __restrict__ wh2o_bf, float* __restrict__ gxbias) {
    int tid = blockIdx.x * 256 + threadIdx.x;
    int np = gridDim.x * 256;
    for (int i = tid; i < HH * EE; i += np) we_bf[i] = (bf16_t)we[i];
    for (int i = tid; i < 384 * HH; i += np) {
        int nrow = i >> 7;                      // row over 384 (HH=128 cols)
        float sc = (nrow < 256) ? SC_RZ : SC_N;
        wih_bf[i] = (bf16_t)(sc * wihf[i]);
        wih_bf[384 * HH + i] = (bf16_t)(sc * wihb[i]);
        whh_bf[i] = (bf16_t)(sc * whhf[i]);
        whh_bf[384 * HH + i] = (bf16_t)(sc * whhb[i]);
    }
    for (int i = tid; i < OO * 256; i += np) wh2o_bf[i] = (bf16_t)wh2o[i];
    if (tid < 768) {
        int dir = tid / 384, n = tid % 384;
        const float* bih = dir ? bihb : bihf;
        const float* bhh = dir ? bhhb : bhhf;
        float sc = (n < 256) ? SC_RZ : SC_N;
        gxbias[tid] = sc * bih[n] + (n < 256 ? sc * bhh[n] : 0.0f);  // bhh_n goes in K3's C-init
    }
}

// -------- K12 (fused K1+K2), 4 timesteps per block, dead-time skip. Dedup
// stage 1 (wave w2 owns t=4tq+w2), fp32 emb gather.
__global__ __launch_bounds__(256) void k12_gx(const int* __restrict__ X,
                                              const float* __restrict__ emb,
                                              const bf16_t* __restrict__ we_bf,
                                              const float* __restrict__ be,
                                              const bf16_t* __restrict__ wih_bf,
                                              const float* __restrict__ gxbias,
                                              const int* __restrict__ lens,
                                              bf16_t* __restrict__ gx3) {
    int blk = blockIdx.x;            // 0..511 = tq*4 + g
    int tq = blk >> 2;
    int g = blk & 3;                 // 16-sample tile
    if (4 * tq >= lens[16 * g]) return;   // uniform: whole block dead

    int lane = threadIdx.x & 63;
    int w2 = threadIdx.x >> 6;       // wave 0..3
    int quad = lane >> 4, col = lane & 15;

    __shared__ bf16_t xs[4][16 * 136];   // 4 xh tiles, row-padded

    // stage 1: wave w2 computes xh tile for t = 4tq + w2 (all 8 n-tiles)
    {
        int t = 4 * tq + w2;
        int v = X[(g * 16 + col) * TT + t];
        bf16x8 a[4];
#pragma unroll
        for (int kc = 0; kc < 4; ++kc)
            a[kc] = ldf8_bf(emb + (size_t)v * EE + kc * 32 + quad * 8);
#pragma unroll
        for (int nt = 0; nt < 8; ++nt) {
            int n = nt * 16 + col;
            floatx4 acc = {0.f, 0.f, 0.f, 0.f};
#pragma unroll
            for (int kc = 0; kc < 4; ++kc) {
                bf16x8 bw = ldb8(we_bf + (size_t)n * EE + kc * 32 + quad * 8);
                acc = __builtin_amdgcn_mfma_f32_16x16x32_bf16(a[kc], bw, acc, 0, 0, 0);
            }
            float bias = be[n];
#pragma unroll
            for (int r = 0; r < 4; ++r)
                xs[w2][(quad * 4 + r) * 136 + n] = (bf16_t)(acc[r] + bias);
        }
    }
    __syncthreads();

    // stage 2: gx = xh @ Wih^T + gxbias, both dirs; Wih loaded once per n-tile
    bf16x8 a2[4][4];
#pragma unroll
    for (int tt = 0; tt < 4; ++tt)
#pragma unroll
        for (int kc = 0; kc < 4; ++kc)
            a2[tt][kc] = ldb8(xs[tt] + col * 136 + kc * 32 + quad * 8);

#pragma unroll 2
    for (int tl = 0; tl < 12; ++tl) {
        int idx = w2 * 12 + tl;          // 0..47
        int dir = idx >= 24;
        int n = (idx - dir * 24) * 16 + col;   // 0..383
        bf16x8 bw[4];
#pragma unroll
        for (int kc = 0; kc < 4; ++kc)
            bw[kc] = ldb8(wih_bf + ((size_t)dir * 384 + n) * HH + kc * 32 + quad * 8);
        float bias = gxbias[dir * 384 + n];
#pragma unroll
        for (int tt = 0; tt < 4; ++tt) {
            int t = 4 * tq + tt;
            floatx4 acc = {0.f, 0.f, 0.f, 0.f};
#pragma unroll
            for (int kc = 0; kc < 4; ++kc)
                acc = __builtin_amdgcn_mfma_f32_16x16x32_bf16(a2[tt][kc], bw[kc], acc, 0, 0, 0);
            bf16x4 pack;
#pragma unroll
            for (int r = 0; r < 4; ++r)
                pack[r] = (__bf16)(acc[r] + bias);   // D row r -> sample 16g+quad*4+r
            *reinterpret_cast<bf16x4*>(
                gx3 + (((size_t)(dir * 16 + 4 * g + quad) * TT + t) * 384 + n) * 4) = pack;
        }
    }
}

// -------- K3 (R13): both directions of a group in ONE 1024-thread block.
// Rationale: per-active-CU pipes were only ~50% busy (MFMA 26% + VALU 24%)
// with 2 waves/SIMD — the step is latency-bound (LDS round-trip + barrier +
// transcendental chain), not issue-bound. fwd/bwd recurrences are independent,
// share Lmax (same barrier count), and ran on DIFFERENT CUs. Co-locating them
// gives 4 waves/SIMD (2 fwd + 2 bwd) — doubled TLP under the same latency
// shadow, zero change to any wave's critical path (R1's failure was the
// opposite move: fewer waves, more per-wave work). Per-dir code is
// byte-identical to the frozen R4/R10 kernel.
#define HPAD 144
#define HBUF (4 * HPAD)
__global__ __launch_bounds__(1024) void k3_gru(const bf16_t* __restrict__ gx3,
                                               const bf16_t* __restrict__ whh_bf,
                                               const float* __restrict__ bhh_f,
                                               const float* __restrict__ bhh_b,
                                               const int* __restrict__ lens,
                                               bf16_t* __restrict__ hist2) {
    int g16 = blockIdx.x;    // 4-sample group: samples 4*g16 .. 4*g16+3
    int tidAll = threadIdx.x;
    int dir = tidAll >> 9;   // waves 0..7 = fwd, 8..15 = bwd
    int tid = tidAll & 511;
    const float* bhh = dir ? bhh_b : bhh_f;

    int w = tid >> 6;        // wave 0..7 within this direction
    int lane = tid & 63;
    int quad = lane >> 4, col = lane & 15;
    int j = 16 * w + col;    // owned hidden column

    __shared__ bf16_t hl2[2][2 * HBUF];   // per-dir double-buffered h
    for (int i = tidAll; i < 4 * HBUF; i += 1024)
        (&hl2[0][0])[i] = (bf16_t)0.f;
    bf16_t* hl = hl2[dir];

    int len1 = lens[4 * g16 + quad];      // this lane's sample
    int Lmax = max(max(lens[4 * g16], lens[4 * g16 + 1]),
                   max(lens[4 * g16 + 2], lens[4 * g16 + 3]));

    float bhn = SC_N * bhh[256 + j];      // n-row scale applied (C-init)

    // Whh B-fragments (pre-converted bf16, pre-scaled), resident for all steps
    bf16x8 Bw[3][4];
#pragma unroll
    for (int gate = 0; gate < 3; ++gate)
#pragma unroll
        for (int kc = 0; kc < 4; ++kc)
            Bw[gate][kc] = ldb8(whh_bf + ((size_t)dir * 384 + gate * 128 + j) * HH + kc * 32 + quad * 8);

    const bf16_t* gbase = gx3 + (size_t)(dir * 16 + g16) * TT * 1536;
    bf16_t* hb = hist2 + (size_t)(dir * 16 + g16) * TT * 512;
    int loff[3];
#pragma unroll
    for (int gate = 0; gate < 3; ++gate)
        loff[gate] = (gate * 128 + j) * 4 + quad;
    int hoff = quad * 128 + j;
    int aoff = (col >> 2) * HPAD + quad * 8;   // broadcast A-read: row m -> sample m>>2

    float h = 0.f;
    int S4 = (Lmax + 3) & ~3;

    // prefetch ring, depth 4 (raw bf16 scalars; convert at consumption).
    __bf16 ring[4][3];
#pragma unroll
    for (int u = 0; u < 4; ++u) {
        int t = dir ? (Lmax - 1 - u) : u;
#pragma unroll
        for (int gate = 0; gate < 3; ++gate)
            ring[u][gate] = gbase[(size_t)t * 1536 + loff[gate]];
    }
    lds_barrier();   // zero-init visible (block-wide: both dirs)

    // saturating stream pointers (replace per-step clamp+mul addressing)
    int gstep = dir ? -1536 : 1536;       // gx3 elements per t
    int hstep = dir ? -512 : 512;         // hist2 elements per t
    const bf16_t* rp0 = gbase + (size_t)(dir ? (Lmax - 5) : 4) * 1536 + loff[0];
    const bf16_t* rp1 = gbase + (size_t)(dir ? (Lmax - 5) : 4) * 1536 + loff[1];
    const bf16_t* rp2 = gbase + (size_t)(dir ? (Lmax - 5) : 4) * 1536 + loff[2];
    bf16_t* hp = hb + (size_t)(dir ? (Lmax - 1) : 0) * 512 + hoff;
    int ulo = dir ? (Lmax - len1) : 0;    // upd  <=>  ulo <= s < uhi
    int uhi = dir ? Lmax : len1;

    for (int sb = 0; sb < S4; sb += 4) {
#pragma unroll
        for (int u = 0; u < 4; ++u) {
            int s = sb + u;
            const bf16_t* hc = hl + (s & 1) * HBUF;
            bf16_t* hn = hl + ((s + 1) & 1) * HBUF;

            // consume ring slot u (loads issued 4 steps ago); prescaled values
            float gx0 = (float)ring[u][0];   // -log2e * gx_r
            float gx1 = (float)ring[u][1];   // -log2e * gx_z
            float gx2 = (float)ring[u][2];   // 2log2e * gx_n

            // A fragments from LDS h (broadcast rows: sample = row >> 2)
            bf16x8 a[4];
#pragma unroll
            for (int kc = 0; kc < 4; ++kc)
                a[kc] = ldb8(hc + aoff + kc * 32);

            // 3 chains; bhn folded into n-gate C-init (compiler-scheduled)
            floatx4 cr = {0.f, 0.f, 0.f, 0.f};
            floatx4 cz = {0.f, 0.f, 0.f, 0.f};
            floatx4 cn = {bhn, bhn, bhn, bhn};
#pragma unroll
            for (int kc = 0; kc < 4; ++kc) {
                cr = __builtin_amdgcn_mfma_f32_16x16x32_bf16(a[kc], Bw[0][kc], cr, 0, 0, 0);
                cz = __builtin_amdgcn_mfma_f32_16x16x32_bf16(a[kc], Bw[1][kc], cz, 0, 0, 0);
                cn = __builtin_amdgcn_mfma_f32_16x16x32_bf16(a[kc], Bw[2][kc], cn, 0, 0, 0);
            }

            // refill ring slot u for step s+4 (pointers saturate at the ends)
            ring[u][0] = *rp0;
            ring[u][1] = *rp1;
            ring[u][2] = *rp2;
            {
                int adv = (s < Lmax - 5) ? gstep : 0;   // scalar select
                rp0 += adv; rp1 += adv; rp2 += adv;
            }

            // all 4 D-regs equal (rows quad*4+r all carry sample quad) -> [0]
            float rg = fast_rcp(1.0f + exp2_f(cr[0] + gx0));       // sigmoid
            float zg = fast_rcp(1.0f + exp2_f(cz[0] + gx1));       // sigmoid
            float v  = fmaf(rg, cn[0], gx2);                       // scaled tanh-arg
            float ng = fmaf(-2.0f, fast_rcp(exp2_f(v) + 1.0f), 1.0f);  // tanh
            float hnew = fmaf(zg, h - ng, ng);                     // (1-z)n + z*h

            bool upd = (s >= ulo) && (s < uhi);
            h = upd ? hnew : h;
            bf16_t h16 = (bf16_t)h;
            hn[quad * HPAD + j] = h16;            // LDS row = sample
            *hp = h16;                            // hist2 per-block region
            hp += (s < Lmax - 1) ? hstep : 0;

            lds_barrier();   // new h visible; old buffer free (both dirs)
        }
    }
}

// -------- K4: score phase only, 4 blocks per sample (256 blocks). Frozen R12.
__global__ __launch_bounds__(512) void k4_score(const bf16_t* __restrict__ hist2,
                                                const bf16_t* __restrict__ wh2o_bf,
                                                const float* __restrict__ bh2o,
                                                const float* __restrict__ uw,
                                                const int* __restrict__ lens,
                                                float* __restrict__ smax_ws) {
    int blk = blockIdx.x;            // b*4 + seg
    int b = blk >> 2, seg = blk & 3;
    int g16 = b >> 2, bl = b & 3;
    int tid = threadIdx.x;
    int lane = tid & 63, wv = tid >> 6;       // 8 waves
    int quad = lane >> 4, col = lane & 15;
    int len = lens[b];

    int p = wv >> 2;         // parity within this segment's chunk pair
    int q = wv & 3;          // tile pair (n-channels 32q..32q+31)
    int ch0 = seg * 2 + p;   // chunks ch0, ch0+8, ch0+16, ...
    int nch = (len + 15) >> 4;

    const bf16_t* hf = hist2 + (size_t)g16 * TT * 512 + bl * 128;        // fwd
    const bf16_t* hbk = hist2 + (size_t)(16 + g16) * TT * 512 + bl * 128; // bwd
    float* sm = smax_ws + (size_t)b * TT * 4;

    int n0 = (q * 2 + 0) * 16 + col;
    int n1 = (q * 2 + 1) * 16 + col;
    float bias0 = bh2o[n0], u0 = uw[n0];
    float bias1 = bh2o[n1], u1 = uw[n1];

    // resident B-fragments (2 n-tiles x 8 kc x 16B = 64 VGPR)
    bf16x8 bw0[8], bw1[8];
#pragma unroll
    for (int kc = 0; kc < 8; ++kc) {
        bw0[kc] = ldb8(wh2o_bf + (size_t)n0 * 256 + kc * 32 + quad * 8);
        bw1[kc] = ldb8(wh2o_bf + (size_t)n1 * 256 + kc * 32 + quad * 8);
    }

    bf16x8 a[8], an[8];
    {   // prime first chunk (ch0*16+15 <= 127 < 512: always valid memory)
        int t = ch0 * 16 + col;
#pragma unroll
        for (int kc = 0; kc < 4; ++kc) {
            a[kc]     = ldb8(hf  + (size_t)t * 512 + kc * 32 + quad * 8);
            a[kc + 4] = ldb8(hbk + (size_t)t * 512 + kc * 32 + quad * 8);
        }
    }
    for (int ch = ch0; ch < nch; ch += 8) {
        int t0 = ch * 16;
        // prefetch this wave's next chunk (clamped; stays in-bounds)
        {
            int tn = (ch + 8 < nch ? t0 + 128 : t0) + col;
#pragma unroll
            for (int kc = 0; kc < 4; ++kc) {
                an[kc]     = ldb8(hf  + (size_t)tn * 512 + kc * 32 + quad * 8);
                an[kc + 4] = ldb8(hbk + (size_t)tn * 512 + kc * 32 + quad * 8);
            }
        }
        float p4[4] = {0.f, 0.f, 0.f, 0.f};
#pragma unroll
        for (int tl = 0; tl < 2; ++tl) {
            float bias = tl ? bias1 : bias0;
            float u = tl ? u1 : u0;
            floatx4 accA = {0.f, 0.f, 0.f, 0.f};
            floatx4 accB = {0.f, 0.f, 0.f, 0.f};
#pragma unroll
            for (int kc = 0; kc < 4; ++kc) {
                bf16x8 bwA = tl ? bw1[kc] : bw0[kc];
                bf16x8 bwB = tl ? bw1[kc + 4] : bw0[kc + 4];
                accA = __builtin_amdgcn_mfma_f32_16x16x32_bf16(a[kc], bwA, accA, 0, 0, 0);
                accB = __builtin_amdgcn_mfma_f32_16x16x32_bf16(a[kc + 4], bwB, accB, 0, 0, 0);
            }
#pragma unroll
            for (int r = 0; r < 4; ++r)
                p4[r] += tanh_f(accA[r] + accB[r] + bias) * u;
        }
        // reduce over the 16 cols of this quad group (D rows = t's)
#pragma unroll
        for (int m = 1; m < 16; m <<= 1)
#pragma unroll
            for (int r = 0; r < 4; ++r)
                p4[r] += __shfl_xor(p4[r], m, 64);
        if (col == 0) {
#pragma unroll
            for (int r = 0; r < 4; ++r)
                sm[(size_t)(t0 + quad * 4 + r) * 4 + q] = p4[r];
        }
#pragma unroll
        for (int kc = 0; kc < 8; ++kc) a[kc] = an[kc];
    }
}

// -------- K5: softmax + pool, one block per sample (64 x 512). Frozen R12.
__global__ __launch_bounds__(512) void k5_pool(const bf16_t* __restrict__ hist2,
                                               const float* __restrict__ smax_ws,
                                               const int* __restrict__ lens,
                                               float* __restrict__ out) {
    int b = blockIdx.x;
    int g16 = b >> 2, bl = b & 3;
    int tid = threadIdx.x;
    int lane = tid & 63, wv = tid >> 6;       // 8 waves
    int len = lens[b];

    __shared__ float alpha[TT];         // 2 KB
    __shared__ float redw[16];          // wave partials
    __shared__ float red2[16 * 32 * 9]; // pool partials, padded stride 9 (18 KB)

    const bf16_t* hf = hist2 + (size_t)g16 * TT * 512 + bl * 128;        // fwd
    const bf16_t* hbk = hist2 + (size_t)(16 + g16) * TT * 512 + bl * 128; // bwd
    const float* sm = smax_ws + (size_t)b * TT * 4;

    // softmax over valid t (thread tid <-> t); wave-local reduce
    int t = tid;
    float s = -1e30f;
    if (t < len) {
        float4 v = *reinterpret_cast<const float4*>(sm + (size_t)t * 4);
        s = (v.x + v.y) + (v.z + v.w);
    }
    float m = s;
#pragma unroll
    for (int off = 1; off <= 32; off <<= 1) m = fmaxf(m, __shfl_xor(m, off, 64));
    if (lane == 0) redw[wv] = m;
    __syncthreads();
    float mx = fmaxf(fmaxf(fmaxf(redw[0], redw[1]), fmaxf(redw[2], redw[3])),
                     fmaxf(fmaxf(redw[4], redw[5]), fmaxf(redw[6], redw[7])));
    float e = (t < len) ? __expf(s - mx) : 0.f;
    alpha[t] = e;
    float smm = e;
#pragma unroll
    for (int off = 1; off <= 32; off <<= 1) smm += __shfl_xor(smm, off, 64);
    if (lane == 0) redw[8 + wv] = smm;
    __syncthreads();
    float inv = fast_rcp(redw[8] + redw[9] + redw[10] + redw[11] +
                         redw[12] + redw[13] + redw[14] + redw[15]);

    // pooled (coalesced): thread = (ts = tid>>5: t stride 16, o = tid&31).
    {
        int ts = tid >> 5, o = tid & 31;
        int dirp = o >> 4;
        int j8 = (o & 15) * 8;
        const bf16_t* hbase = (dirp ? hbk : hf) + j8;
        float acc8[8];
#pragma unroll
        for (int ee = 0; ee < 8; ++ee) acc8[ee] = 0.f;
        for (int tt2 = ts; tt2 < len; tt2 += 16) {
            float al = alpha[tt2];
            bf16x8 hv = ldb8(hbase + (size_t)tt2 * 512);
#pragma unroll
            for (int ee = 0; ee < 8; ++ee) acc8[ee] = fmaf(al, (float)hv[ee], acc8[ee]);
        }
#pragma unroll
        for (int ee = 0; ee < 8; ++ee) red2[(ts * 32 + o) * 9 + ee] = acc8[ee];
        __syncthreads();
        if (tid < 256) {
            int c = tid;                       // output channel
            int dir2 = c >> 7, rem = c & 127;
            int oo = dir2 * 16 + (rem >> 3), ee = c & 7;
            float acc = 0.f;
#pragma unroll
            for (int qq = 0; qq < 16; ++qq) acc += red2[(qq * 32 + oo) * 9 + ee];
            out[(size_t)b * 256 + c] = acc * inv;
        }
    }
}

extern "C" void kernel_launch(void* const* d_in, const int* in_sizes, int n_in,
                              void* d_out, int out_size, void* d_ws, size_t ws_size,
                              hipStream_t stream) {
    const int* X       = (const int*)d_in[0];
    const int* lens    = (const int*)d_in[1];
    const float* emb   = (const float*)d_in[3];
    const float* We2i  = (const float*)d_in[4];
    const float* be2i  = (const float*)d_in[5];
    const float* Wihf  = (const float*)d_in[6];
    const float* Whhf  = (const float*)d_in[7];
    const float* bihf  = (const float*)d_in[8];
    const float* bhhf  = (const float*)d_in[9];
    const float* Wihb  = (const float*)d_in[10];
    const float* Whhb  = (const float*)d_in[11];
    const float* bihb  = (const float*)d_in[12];
    const float* bhhb  = (const float*)d_in[13];
    const float* Wh2o  = (const float*)d_in[14];
    const float* bh2o  = (const float*)d_in[15];
    const float* uw    = (const float*)d_in[16];

    char* ws = (char*)d_ws;
    size_t off = 0;
    bf16_t* we_bf = (bf16_t*)(ws + off);   off += (size_t)HH * EE * 2;          // 32 KB
    bf16_t* wih_bf = (bf16_t*)(ws + off);  off += (size_t)2 * 384 * HH * 2;     // 192 KB
    bf16_t* whh_bf = (bf16_t*)(ws + off);  off += (size_t)2 * 384 * HH * 2;     // 192 KB
    bf16_t* wh2o_bf = (bf16_t*)(ws + off); off += (size_t)OO * 256 * 2;         // 64 KB
    float* gxbias = (float*)(ws + off);    off += 768 * 4;                      // 3 KB
    off = (off + 255) & ~(size_t)255;
    float* smax_ws = (float*)(ws + off);   off += (size_t)BB * TT * 4 * 4;      // 512 KB
    off = (off + 255) & ~(size_t)255;
    bf16_t* gx3 = (bf16_t*)(ws + off);     off += (size_t)32 * TT * 384 * 4 * 2; // 50.3 MB
    bf16_t* hist2 = (bf16_t*)(ws + off);   off += (size_t)32 * TT * 4 * 128 * 2; // 16.8 MB

    float* out = (float*)d_out;

    k0_conv<<<dim3(256), dim3(256), 0, stream>>>(We2i, Wihf, Wihb, Whhf, Whhb,
                                                 Wh2o, bihf, bhhf, bihb, bhhb,
                                                 we_bf, wih_bf, whh_bf, wh2o_bf, gxbias);
    k12_gx<<<dim3(TT), dim3(256), 0, stream>>>(X, emb, we_bf, be2i, wih_bf, gxbias, lens, gx3);
    k3_gru<<<dim3(16), dim3(1024), 0, stream>>>(gx3, whh_bf, bhhf, bhhb, lens, hist2);
    k4_score<<<dim3(BB * 4), dim3(512), 0, stream>>>(hist2, wh2o_bf, bh2o, uw, lens, smax_ws);
    k5_pool<<<dim3(BB), dim3(512), 0, stream>>>(hist2, smax_ws, lens, out);
}

// Round 14
// 326.664 us; speedup vs baseline: 1.3764x; 1.3764x over previous
//
#include <hip/hip_runtime.h>
#include <hip/hip_bf16.h>

// Shapes (fixed by the problem)
#define VV 50000
#define EE 128
#define HH 128
#define OO 128
#define BB 64
#define TT 512

typedef __bf16 bf16_t;
typedef __attribute__((ext_vector_type(8))) __bf16 bf16x8;
typedef __attribute__((ext_vector_type(4))) __bf16 bf16x4;
typedef __attribute__((ext_vector_type(4))) float floatx4;

// exp2-prescale constants: sigmoid/tanh computed via v_exp_f32 (=2^x) with
// log2e folded into the r/z/n weight rows in k0 (r,z: -log2e; n: +2*log2e).
#define SC_RZ (-1.4426950408889634f)
#define SC_N  (2.8853900817779268f)

__device__ __forceinline__ bf16x8 ldb8(const bf16_t* p) {
    return *reinterpret_cast<const bf16x8*>(p);
}

// load 8 consecutive fp32, round to bf16 fragment (two float4 loads)
__device__ __forceinline__ bf16x8 ldf8_bf(const float* p) {
    const float4* q = reinterpret_cast<const float4*>(p);
    float4 u = q[0], v = q[1];
    bf16x8 r;
    r[0] = (__bf16)u.x; r[1] = (__bf16)u.y; r[2] = (__bf16)u.z; r[3] = (__bf16)u.w;
    r[4] = (__bf16)v.x; r[5] = (__bf16)v.y; r[6] = (__bf16)v.z; r[7] = (__bf16)v.w;
    return r;
}

__device__ __forceinline__ float fast_rcp(float x) { return __builtin_amdgcn_rcpf(x); }
__device__ __forceinline__ float exp2_f(float x) { return __builtin_amdgcn_exp2f(x); }
__device__ __forceinline__ float tanh_f(float x) {
    float e = __expf(2.0f * x);
    return 1.0f - 2.0f * fast_rcp(e + 1.0f);
}

// LDS-only barrier: wait LDS ops, sync — do NOT drain vmcnt (hist stores and
// gx ring-prefetch loads stay in flight across steps).
__device__ __forceinline__ void lds_barrier() {
    asm volatile("s_waitcnt lgkmcnt(0)\n\ts_barrier" ::: "memory");
}

// -------- K0: preconvert weights fp32->bf16 + fold gx bias (weights only).
__global__ __launch_bounds__(256) void k0_conv(
    const float* __restrict__ we,
    const float* __restrict__ wihf, const float* __restrict__ wihb,
    const float* __restrict__ whhf, const float* __restrict__ whhb,
    const float* __restrict__ wh2o,
    const float* __restrict__ bihf, const float* __restrict__ bhhf,
    const float* __restrict__ bihb, const float* __restrict__ bhhb,
    bf16_t* __restrict__ we_bf,
    bf16_t* __restrict__ wih_bf, bf16_t* __restrict__ whh_bf,
    bf16_t* __restrict__ wh2o_bf, float* __restrict__ gxbias) {
    int tid = blockIdx.x * 256 + threadIdx.x;
    int np = gridDim.x * 256;
    for (int i = tid; i < HH * EE; i += np) we_bf[i] = (bf16_t)we[i];
    for (int i = tid; i < 384 * HH; i += np) {
        int nrow = i >> 7;                      // row over 384 (HH=128 cols)
        float sc = (nrow < 256) ? SC_RZ : SC_N;
        wih_bf[i] = (bf16_t)(sc * wihf[i]);
        wih_bf[384 * HH + i] = (bf16_t)(sc * wihb[i]);
        whh_bf[i] = (bf16_t)(sc * whhf[i]);
        whh_bf[384 * HH + i] = (bf16_t)(sc * whhb[i]);
    }
    for (int i = tid; i < OO * 256; i += np) wh2o_bf[i] = (bf16_t)wh2o[i];
    if (tid < 768) {
        int dir = tid / 384, n = tid % 384;
        const float* bih = dir ? bihb : bihf;
        const float* bhh = dir ? bhhb : bhhf;
        float sc = (n < 256) ? SC_RZ : SC_N;
        gxbias[tid] = sc * bih[n] + (n < 256 ? sc * bhh[n] : 0.0f);  // bhh_n goes in K3's C-init
    }
}

// -------- K12 (fused K1+K2), 4 timesteps per block, dead-time skip. Dedup
// stage 1 (wave w2 owns t=4tq+w2), fp32 emb gather.
__global__ __launch_bounds__(256) void k12_gx(const int* __restrict__ X,
                                              const float* __restrict__ emb,
                                              const bf16_t* __restrict__ we_bf,
                                              const float* __restrict__ be,
                                              const bf16_t* __restrict__ wih_bf,
                                              const float* __restrict__ gxbias,
                                              const int* __restrict__ lens,
                                              bf16_t* __restrict__ gx3) {
    int blk = blockIdx.x;            // 0..511 = tq*4 + g
    int tq = blk >> 2;
    int g = blk & 3;                 // 16-sample tile
    if (4 * tq >= lens[16 * g]) return;   // uniform: whole block dead

    int lane = threadIdx.x & 63;
    int w2 = threadIdx.x >> 6;       // wave 0..3
    int quad = lane >> 4, col = lane & 15;

    __shared__ bf16_t xs[4][16 * 136];   // 4 xh tiles, row-padded

    // stage 1: wave w2 computes xh tile for t = 4tq + w2 (all 8 n-tiles)
    {
        int t = 4 * tq + w2;
        int v = X[(g * 16 + col) * TT + t];
        bf16x8 a[4];
#pragma unroll
        for (int kc = 0; kc < 4; ++kc)
            a[kc] = ldf8_bf(emb + (size_t)v * EE + kc * 32 + quad * 8);
#pragma unroll
        for (int nt = 0; nt < 8; ++nt) {
            int n = nt * 16 + col;
            floatx4 acc = {0.f, 0.f, 0.f, 0.f};
#pragma unroll
            for (int kc = 0; kc < 4; ++kc) {
                bf16x8 bw = ldb8(we_bf + (size_t)n * EE + kc * 32 + quad * 8);
                acc = __builtin_amdgcn_mfma_f32_16x16x32_bf16(a[kc], bw, acc, 0, 0, 0);
            }
            float bias = be[n];
#pragma unroll
            for (int r = 0; r < 4; ++r)
                xs[w2][(quad * 4 + r) * 136 + n] = (bf16_t)(acc[r] + bias);
        }
    }
    __syncthreads();

    // stage 2: gx = xh @ Wih^T + gxbias, both dirs; Wih loaded once per n-tile
    bf16x8 a2[4][4];
#pragma unroll
    for (int tt = 0; tt < 4; ++tt)
#pragma unroll
        for (int kc = 0; kc < 4; ++kc)
            a2[tt][kc] = ldb8(xs[tt] + col * 136 + kc * 32 + quad * 8);

#pragma unroll 2
    for (int tl = 0; tl < 12; ++tl) {
        int idx = w2 * 12 + tl;          // 0..47
        int dir = idx >= 24;
        int n = (idx - dir * 24) * 16 + col;   // 0..383
        bf16x8 bw[4];
#pragma unroll
        for (int kc = 0; kc < 4; ++kc)
            bw[kc] = ldb8(wih_bf + ((size_t)dir * 384 + n) * HH + kc * 32 + quad * 8);
        float bias = gxbias[dir * 384 + n];
#pragma unroll
        for (int tt = 0; tt < 4; ++tt) {
            int t = 4 * tq + tt;
            floatx4 acc = {0.f, 0.f, 0.f, 0.f};
#pragma unroll
            for (int kc = 0; kc < 4; ++kc)
                acc = __builtin_amdgcn_mfma_f32_16x16x32_bf16(a2[tt][kc], bw[kc], acc, 0, 0, 0);
            bf16x4 pack;
#pragma unroll
            for (int r = 0; r < 4; ++r)
                pack[r] = (__bf16)(acc[r] + bias);   // D row r -> sample 16g+quad*4+r
            *reinterpret_cast<bf16x4*>(
                gx3 + (((size_t)(dir * 16 + 4 * g + quad) * TT + t) * 384 + n) * 4) = pack;
        }
    }
}

// -------- K3: masked GRU recurrence — FROZEN at R4/R10 (177 us measured).
// Structural map (all counter-verified): 4 waves (R1 +83us), MFMA reorder
// (R2 +30us), chain-split (R11 +2.5us), 16-wave dir-merge (R13 +122us) all
// regress. 8 waves x 1 block/CU x this spine = empirical optimum; the step
// is bounded by LDS round-trip + 8-wave barrier + transcendental tail.
#define HPAD 144
#define HBUF (4 * HPAD)
__global__ __launch_bounds__(512) void k3_gru(const bf16_t* __restrict__ gx3,
                                              const bf16_t* __restrict__ whh_bf,
                                              const float* __restrict__ bhh_f,
                                              const float* __restrict__ bhh_b,
                                              const int* __restrict__ lens,
                                              bf16_t* __restrict__ hist2) {
    int g16 = blockIdx.x;    // 4-sample group: samples 4*g16 .. 4*g16+3
    int dir = blockIdx.y;
    const float* bhh = dir ? bhh_b : bhh_f;

    int tid = threadIdx.x;
    int w = tid >> 6;        // wave 0..7
    int lane = tid & 63;
    int quad = lane >> 4, col = lane & 15;
    int j = 16 * w + col;    // owned hidden column

    __shared__ bf16_t hl[2 * HBUF];   // double-buffered h, 4 rows (samples)
    for (int i = tid; i < 2 * HBUF; i += 512) hl[i] = (bf16_t)0.f;

    int len1 = lens[4 * g16 + quad];      // this lane's sample
    int Lmax = max(max(lens[4 * g16], lens[4 * g16 + 1]),
                   max(lens[4 * g16 + 2], lens[4 * g16 + 3]));

    float bhn = SC_N * bhh[256 + j];      // n-row scale applied (C-init)

    // Whh B-fragments (pre-converted bf16, pre-scaled), resident for all steps
    bf16x8 Bw[3][4];
#pragma unroll
    for (int gate = 0; gate < 3; ++gate)
#pragma unroll
        for (int kc = 0; kc < 4; ++kc)
            Bw[gate][kc] = ldb8(whh_bf + ((size_t)dir * 384 + gate * 128 + j) * HH + kc * 32 + quad * 8);

    const bf16_t* gbase = gx3 + (size_t)(dir * 16 + g16) * TT * 1536;
    bf16_t* hb = hist2 + (size_t)(dir * 16 + g16) * TT * 512;
    int loff[3];
#pragma unroll
    for (int gate = 0; gate < 3; ++gate)
        loff[gate] = (gate * 128 + j) * 4 + quad;
    int hoff = quad * 128 + j;
    int aoff = (col >> 2) * HPAD + quad * 8;   // broadcast A-read: row m -> sample m>>2

    float h = 0.f;
    int S4 = (Lmax + 3) & ~3;

    // prefetch ring, depth 4 (raw bf16 scalars; convert at consumption).
    __bf16 ring[4][3];
#pragma unroll
    for (int u = 0; u < 4; ++u) {
        int t = dir ? (Lmax - 1 - u) : u;
#pragma unroll
        for (int gate = 0; gate < 3; ++gate)
            ring[u][gate] = gbase[(size_t)t * 1536 + loff[gate]];
    }
    lds_barrier();   // zero-init visible

    // saturating stream pointers (replace per-step clamp+mul addressing)
    int gstep = dir ? -1536 : 1536;       // gx3 elements per t
    int hstep = dir ? -512 : 512;         // hist2 elements per t
    const bf16_t* rp0 = gbase + (size_t)(dir ? (Lmax - 5) : 4) * 1536 + loff[0];
    const bf16_t* rp1 = gbase + (size_t)(dir ? (Lmax - 5) : 4) * 1536 + loff[1];
    const bf16_t* rp2 = gbase + (size_t)(dir ? (Lmax - 5) : 4) * 1536 + loff[2];
    bf16_t* hp = hb + (size_t)(dir ? (Lmax - 1) : 0) * 512 + hoff;
    int ulo = dir ? (Lmax - len1) : 0;    // upd  <=>  ulo <= s < uhi
    int uhi = dir ? Lmax : len1;

    for (int sb = 0; sb < S4; sb += 4) {
#pragma unroll
        for (int u = 0; u < 4; ++u) {
            int s = sb + u;
            const bf16_t* hc = hl + (s & 1) * HBUF;
            bf16_t* hn = hl + ((s + 1) & 1) * HBUF;

            // consume ring slot u (loads issued 4 steps ago); prescaled values
            float gx0 = (float)ring[u][0];   // -log2e * gx_r
            float gx1 = (float)ring[u][1];   // -log2e * gx_z
            float gx2 = (float)ring[u][2];   // 2log2e * gx_n

            // A fragments from LDS h (broadcast rows: sample = row >> 2)
            bf16x8 a[4];
#pragma unroll
            for (int kc = 0; kc < 4; ++kc)
                a[kc] = ldb8(hc + aoff + kc * 32);

            // 3 chains; bhn folded into n-gate C-init (compiler-scheduled)
            floatx4 cr = {0.f, 0.f, 0.f, 0.f};
            floatx4 cz = {0.f, 0.f, 0.f, 0.f};
            floatx4 cn = {bhn, bhn, bhn, bhn};
#pragma unroll
            for (int kc = 0; kc < 4; ++kc) {
                cr = __builtin_amdgcn_mfma_f32_16x16x32_bf16(a[kc], Bw[0][kc], cr, 0, 0, 0);
                cz = __builtin_amdgcn_mfma_f32_16x16x32_bf16(a[kc], Bw[1][kc], cz, 0, 0, 0);
                cn = __builtin_amdgcn_mfma_f32_16x16x32_bf16(a[kc], Bw[2][kc], cn, 0, 0, 0);
            }

            // refill ring slot u for step s+4 (pointers saturate at the ends)
            ring[u][0] = *rp0;
            ring[u][1] = *rp1;
            ring[u][2] = *rp2;
            {
                int adv = (s < Lmax - 5) ? gstep : 0;   // scalar select
                rp0 += adv; rp1 += adv; rp2 += adv;
            }

            // all 4 D-regs equal (rows quad*4+r all carry sample quad) -> [0]
            float rg = fast_rcp(1.0f + exp2_f(cr[0] + gx0));       // sigmoid
            float zg = fast_rcp(1.0f + exp2_f(cz[0] + gx1));       // sigmoid
            float v  = fmaf(rg, cn[0], gx2);                       // scaled tanh-arg
            float ng = fmaf(-2.0f, fast_rcp(exp2_f(v) + 1.0f), 1.0f);  // tanh
            float hnew = fmaf(zg, h - ng, ng);                     // (1-z)n + z*h

            bool upd = (s >= ulo) && (s < uhi);
            h = upd ? hnew : h;
            bf16_t h16 = (bf16_t)h;
            hn[quad * HPAD + j] = h16;            // LDS row = sample
            *hp = h16;                            // hist2 per-block region
            hp += (s < Lmax - 1) ? hstep : 0;

            lds_barrier();   // new h visible; old buffer free
        }
    }
}

// -------- K4: score phase only, 4 blocks per sample (256 blocks). Frozen R12.
__global__ __launch_bounds__(512) void k4_score(const bf16_t* __restrict__ hist2,
                                                const bf16_t* __restrict__ wh2o_bf,
                                                const float* __restrict__ bh2o,
                                                const float* __restrict__ uw,
                                                const int* __restrict__ lens,
                                                float* __restrict__ smax_ws) {
    int blk = blockIdx.x;            // b*4 + seg
    int b = blk >> 2, seg = blk & 3;
    int g16 = b >> 2, bl = b & 3;
    int tid = threadIdx.x;
    int lane = tid & 63, wv = tid >> 6;       // 8 waves
    int quad = lane >> 4, col = lane & 15;
    int len = lens[b];

    int p = wv >> 2;         // parity within this segment's chunk pair
    int q = wv & 3;          // tile pair (n-channels 32q..32q+31)
    int ch0 = seg * 2 + p;   // chunks ch0, ch0+8, ch0+16, ...
    int nch = (len + 15) >> 4;

    const bf16_t* hf = hist2 + (size_t)g16 * TT * 512 + bl * 128;        // fwd
    const bf16_t* hbk = hist2 + (size_t)(16 + g16) * TT * 512 + bl * 128; // bwd
    float* sm = smax_ws + (size_t)b * TT * 4;

    int n0 = (q * 2 + 0) * 16 + col;
    int n1 = (q * 2 + 1) * 16 + col;
    float bias0 = bh2o[n0], u0 = uw[n0];
    float bias1 = bh2o[n1], u1 = uw[n1];

    // resident B-fragments (2 n-tiles x 8 kc x 16B = 64 VGPR)
    bf16x8 bw0[8], bw1[8];
#pragma unroll
    for (int kc = 0; kc < 8; ++kc) {
        bw0[kc] = ldb8(wh2o_bf + (size_t)n0 * 256 + kc * 32 + quad * 8);
        bw1[kc] = ldb8(wh2o_bf + (size_t)n1 * 256 + kc * 32 + quad * 8);
    }

    bf16x8 a[8], an[8];
    {   // prime first chunk (ch0*16+15 <= 127 < 512: always valid memory)
        int t = ch0 * 16 + col;
#pragma unroll
        for (int kc = 0; kc < 4; ++kc) {
            a[kc]     = ldb8(hf  + (size_t)t * 512 + kc * 32 + quad * 8);
            a[kc + 4] = ldb8(hbk + (size_t)t * 512 + kc * 32 + quad * 8);
        }
    }
    for (int ch = ch0; ch < nch; ch += 8) {
        int t0 = ch * 16;
        // prefetch this wave's next chunk (clamped; stays in-bounds)
        {
            int tn = (ch + 8 < nch ? t0 + 128 : t0) + col;
#pragma unroll
            for (int kc = 0; kc < 4; ++kc) {
                an[kc]     = ldb8(hf  + (size_t)tn * 512 + kc * 32 + quad * 8);
                an[kc + 4] = ldb8(hbk + (size_t)tn * 512 + kc * 32 + quad * 8);
            }
        }
        float p4[4] = {0.f, 0.f, 0.f, 0.f};
#pragma unroll
        for (int tl = 0; tl < 2; ++tl) {
            float bias = tl ? bias1 : bias0;
            float u = tl ? u1 : u0;
            floatx4 accA = {0.f, 0.f, 0.f, 0.f};
            floatx4 accB = {0.f, 0.f, 0.f, 0.f};
#pragma unroll
            for (int kc = 0; kc < 4; ++kc) {
                bf16x8 bwA = tl ? bw1[kc] : bw0[kc];
                bf16x8 bwB = tl ? bw1[kc + 4] : bw0[kc + 4];
                accA = __builtin_amdgcn_mfma_f32_16x16x32_bf16(a[kc], bwA, accA, 0, 0, 0);
                accB = __builtin_amdgcn_mfma_f32_16x16x32_bf16(a[kc + 4], bwB, accB, 0, 0, 0);
            }
#pragma unroll
            for (int r = 0; r < 4; ++r)
                p4[r] += tanh_f(accA[r] + accB[r] + bias) * u;
        }
        // reduce over the 16 cols of this quad group (D rows = t's)
#pragma unroll
        for (int m = 1; m < 16; m <<= 1)
#pragma unroll
            for (int r = 0; r < 4; ++r)
                p4[r] += __shfl_xor(p4[r], m, 64);
        if (col == 0) {
#pragma unroll
            for (int r = 0; r < 4; ++r)
                sm[(size_t)(t0 + quad * 4 + r) * 4 + q] = p4[r];
        }
#pragma unroll
        for (int kc = 0; kc < 8; ++kc) a[kc] = an[kc];
    }
}

// -------- K5: softmax + pool, one block per sample (64 x 512). Frozen R12.
__global__ __launch_bounds__(512) void k5_pool(const bf16_t* __restrict__ hist2,
                                               const float* __restrict__ smax_ws,
                                               const int* __restrict__ lens,
                                               float* __restrict__ out) {
    int b = blockIdx.x;
    int g16 = b >> 2, bl = b & 3;
    int tid = threadIdx.x;
    int lane = tid & 63, wv = tid >> 6;       // 8 waves
    int len = lens[b];

    __shared__ float alpha[TT];         // 2 KB
    __shared__ float redw[16];          // wave partials
    __shared__ float red2[16 * 32 * 9]; // pool partials, padded stride 9 (18 KB)

    const bf16_t* hf = hist2 + (size_t)g16 * TT * 512 + bl * 128;        // fwd
    const bf16_t* hbk = hist2 + (size_t)(16 + g16) * TT * 512 + bl * 128; // bwd
    const float* sm = smax_ws + (size_t)b * TT * 4;

    // softmax over valid t (thread tid <-> t); wave-local reduce
    int t = tid;
    float s = -1e30f;
    if (t < len) {
        float4 v = *reinterpret_cast<const float4*>(sm + (size_t)t * 4);
        s = (v.x + v.y) + (v.z + v.w);
    }
    float m = s;
#pragma unroll
    for (int off = 1; off <= 32; off <<= 1) m = fmaxf(m, __shfl_xor(m, off, 64));
    if (lane == 0) redw[wv] = m;
    __syncthreads();
    float mx = fmaxf(fmaxf(fmaxf(redw[0], redw[1]), fmaxf(redw[2], redw[3])),
                     fmaxf(fmaxf(redw[4], redw[5]), fmaxf(redw[6], redw[7])));
    float e = (t < len) ? __expf(s - mx) : 0.f;
    alpha[t] = e;
    float smm = e;
#pragma unroll
    for (int off = 1; off <= 32; off <<= 1) smm += __shfl_xor(smm, off, 64);
    if (lane == 0) redw[8 + wv] = smm;
    __syncthreads();
    float inv = fast_rcp(redw[8] + redw[9] + redw[10] + redw[11] +
                         redw[12] + redw[13] + redw[14] + redw[15]);

    // pooled (coalesced): thread = (ts = tid>>5: t stride 16, o = tid&31).
    {
        int ts = tid >> 5, o = tid & 31;
        int dirp = o >> 4;
        int j8 = (o & 15) * 8;
        const bf16_t* hbase = (dirp ? hbk : hf) + j8;
        float acc8[8];
#pragma unroll
        for (int ee = 0; ee < 8; ++ee) acc8[ee] = 0.f;
        for (int tt2 = ts; tt2 < len; tt2 += 16) {
            float al = alpha[tt2];
            bf16x8 hv = ldb8(hbase + (size_t)tt2 * 512);
#pragma unroll
            for (int ee = 0; ee < 8; ++ee) acc8[ee] = fmaf(al, (float)hv[ee], acc8[ee]);
        }
#pragma unroll
        for (int ee = 0; ee < 8; ++ee) red2[(ts * 32 + o) * 9 + ee] = acc8[ee];
        __syncthreads();
        if (tid < 256) {
            int c = tid;                       // output channel
            int dir2 = c >> 7, rem = c & 127;
            int oo = dir2 * 16 + (rem >> 3), ee = c & 7;
            float acc = 0.f;
#pragma unroll
            for (int qq = 0; qq < 16; ++qq) acc += red2[(qq * 32 + oo) * 9 + ee];
            out[(size_t)b * 256 + c] = acc * inv;
        }
    }
}

extern "C" void kernel_launch(void* const* d_in, const int* in_sizes, int n_in,
                              void* d_out, int out_size, void* d_ws, size_t ws_size,
                              hipStream_t stream) {
    const int* X       = (const int*)d_in[0];
    const int* lens    = (const int*)d_in[1];
    const float* emb   = (const float*)d_in[3];
    const float* We2i  = (const float*)d_in[4];
    const float* be2i  = (const float*)d_in[5];
    const float* Wihf  = (const float*)d_in[6];
    const float* Whhf  = (const float*)d_in[7];
    const float* bihf  = (const float*)d_in[8];
    const float* bhhf  = (const float*)d_in[9];
    const float* Wihb  = (const float*)d_in[10];
    const float* Whhb  = (const float*)d_in[11];
    const float* bihb  = (const float*)d_in[12];
    const float* bhhb  = (const float*)d_in[13];
    const float* Wh2o  = (const float*)d_in[14];
    const float* bh2o  = (const float*)d_in[15];
    const float* uw    = (const float*)d_in[16];

    char* ws = (char*)d_ws;
    size_t off = 0;
    bf16_t* we_bf = (bf16_t*)(ws + off);   off += (size_t)HH * EE * 2;          // 32 KB
    bf16_t* wih_bf = (bf16_t*)(ws + off);  off += (size_t)2 * 384 * HH * 2;     // 192 KB
    bf16_t* whh_bf = (bf16_t*)(ws + off);  off += (size_t)2 * 384 * HH * 2;     // 192 KB
    bf16_t* wh2o_bf = (bf16_t*)(ws + off); off += (size_t)OO * 256 * 2;         // 64 KB
    float* gxbias = (float*)(ws + off);    off += 768 * 4;                      // 3 KB
    off = (off + 255) & ~(size_t)255;
    float* smax_ws = (float*)(ws + off);   off += (size_t)BB * TT * 4 * 4;      // 512 KB
    off = (off + 255) & ~(size_t)255;
    bf16_t* gx3 = (bf16_t*)(ws + off);     off += (size_t)32 * TT * 384 * 4 * 2; // 50.3 MB
    bf16_t* hist2 = (bf16_t*)(ws + off);   off += (size_t)32 * TT * 4 * 128 * 2; // 16.8 MB

    float* out = (float*)d_out;

    k0_conv<<<dim3(256), dim3(256), 0, stream>>>(We2i, Wihf, Wihb, Whhf, Whhb,
                                                 Wh2o, bihf, bhhf, bihb, bhhb,
                                                 we_bf, wih_bf, whh_bf, wh2o_bf, gxbias);
    k12_gx<<<dim3(TT), dim3(256), 0, stream>>>(X, emb, we_bf, be2i, wih_bf, gxbias, lens, gx3);
    k3_gru<<<dim3(16, 2), dim3(512), 0, stream>>>(gx3, whh_bf, bhhf, bhhb, lens, hist2);
    k4_score<<<dim3(BB * 4), dim3(512), 0, stream>>>(hist2, wh2o_bf, bh2o, uw, lens, smax_ws);
    k5_pool<<<dim3(BB), dim3(512), 0, stream>>>(hist2, smax_ws, lens, out);
}